// Round 12
// baseline (179.998 us; speedup 1.0000x reference)
//
#include <hip/hip_runtime.h>
#include <hip/hip_fp16.h>
#include <math.h>

#define NN 10000
#define EE 160000
#define HID 128
constexpr int N128 = NN * HID;
constexpr int PST = 1024;   // pack stride (halves): [k2_0 k2_1 | k3_0 k3_1 k3_2 | h0 h1 h2]
constexpr int H0 = 640;     // h region offset (halves)

typedef _Float16 f16;
typedef f16 half8 __attribute__((ext_vector_type(8)));
typedef f16 f16x2 __attribute__((ext_vector_type(2)));
typedef float f32x4 __attribute__((ext_vector_type(4)));

#if __has_builtin(__builtin_amdgcn_fdot2)
__device__ inline float fdot2(f16x2 a, f16x2 b, float c) { return __builtin_amdgcn_fdot2(a, b, c, false); }
#else
__device__ inline float fdot2(f16x2 a, f16x2 b, float c) {
    return fmaf((float)a[0], (float)b[0], fmaf((float)a[1], (float)b[1], c));
}
#endif

// ---------------- degree count (by dst) ----------------
__global__ __launch_bounds__(256) void cnt_count(const int* __restrict__ dst, int* __restrict__ cnt) {
    int e = blockIdx.x * 256 + threadIdx.x;
    if (e < EE) atomicAdd(&cnt[dst[e]], 1);
}

// ---------------- single-block scan -> rowptr + rowfill (scatter cursors) + dinv ----------------
__global__ __launch_bounds__(256) void scan_rowptr(const int* __restrict__ cnt, int* __restrict__ rowptr,
                                                   int* __restrict__ rowfill, float* __restrict__ dinv) {
    __shared__ int part[256];
    const int PER = (NN + 255) / 256;  // 40
    int t = threadIdx.x;
    int base = t * PER;
    int sum = 0;
    for (int i = 0; i < PER; ++i) {
        int idx = base + i;
        if (idx < NN) {
            int c = cnt[idx];
            sum += c;
            dinv[idx] = rsqrtf((float)c + 1.0f);  // +1 self-loop
        }
    }
    part[t] = sum;
    __syncthreads();
    for (int ofs = 1; ofs < 256; ofs <<= 1) {
        int v = (t >= ofs) ? part[t - ofs] : 0;
        __syncthreads();
        part[t] += v;
        __syncthreads();
    }
    int run = (t > 0) ? part[t - 1] : 0;
    for (int i = 0; i < PER; ++i) {
        int idx = base + i;
        if (idx <= NN) rowptr[idx] = run;
        if (idx < NN) { rowfill[idx] = run; run += cnt[idx]; }
    }
}

__global__ __launch_bounds__(256) void scatter_edges(const int* __restrict__ ei,
                                                     int* __restrict__ rowfill,
                                                     int* __restrict__ esorted) {
    int e = blockIdx.x * 256 + threadIdx.x;
    if (e < EE) {
        int s = ei[e], d = ei[EE + e];
        int pos = atomicAdd(&rowfill[d], 1);
        esorted[pos] = s;
    }
}

// ---------------- prep: transpose 9 mats (blocks 0..8) + zero cnt (blocks 9..24) ----------------
// slots: 0=W1, 1..3=Wv[0..2], 4=W2(64 col), 5=Wq[1], 6=Wq[2], 7=Wk[1], 8=Wk[2]
__global__ __launch_bounds__(256) void prep_fused(const float* __restrict__ W1, const float* __restrict__ Wq,
                                                  const float* __restrict__ Wk, const float* __restrict__ Wv,
                                                  const float* __restrict__ W2, f16* __restrict__ Wt,
                                                  int4* __restrict__ zbuf) {
    int b = blockIdx.x;
    int t = threadIdx.x;
    if (b >= 9) {
        zbuf[(b - 9) * 256 + t] = make_int4(0, 0, 0, 0);  // 16 blocks x 4KB = 64KB (cnt)
        return;
    }
    f16* dst = Wt + (size_t)b * 16384;
    if (b == 4) {  // W2: 128k x 64oc
        int oc = t & 63, k0 = (t >> 6) * 32;
        for (int kk = 0; kk < 32; ++kk) {
            int k = k0 + kk;
            dst[oc * 128 + k] = (f16)W2[(size_t)k * 64 + oc];
        }
        return;
    }
    const float* src = (b == 0) ? W1
                     : (b <= 3) ? Wv + (size_t)(b - 1) * 16384
                     : (b == 5) ? Wq + 16384
                     : (b == 6) ? Wq + 2 * 16384
                     : (b == 7) ? Wk + 16384
                                : Wk + 2 * 16384;
    int oc = t >> 1;
    int k0 = (t & 1) * 64;
    for (int kk = 0; kk < 64; ++kk) {
        int k = k0 + kk;
        dst[oc * 128 + k] = (f16)src[k * 128 + oc];
    }
}

// ---------------- fused GEMM: stage1 (relu V-proj) + up to 3 projections from LDS-resident h + optional final ----------------
struct Proj { const f16* Wt; const float* bias; f16* out; int ldo; };
struct FJob {
    const void* in; int inF32; int ldi;
    const f16* Wt; const float* bias; const float* rowscale;
    f16* out; int ldo; int writeOut;
    int nproj; Proj proj[3];
    int doFinal; const f16* Wt2; const float* bias2; float* fout;
};

__global__ __launch_bounds__(256) void gemm_fused(FJob jb, int nrows) {
    __shared__ f16 Xl[64 * 128];
    __shared__ f16 Wl[128 * 128];
    const int t = threadIdx.x;
    const int row0 = blockIdx.x * 64;

    half8 zero8;
#pragma unroll
    for (int z = 0; z < 8; ++z) zero8[z] = (f16)0.f;

    // stage X (64 rows x 16 chunks, swizzled)
#pragma unroll
    for (int it = 0; it < 4; ++it) {
        int idx = t + it * 256;
        int r = idx >> 4, c = idx & 15;
        int gr = row0 + r;
        half8 v = zero8;
        if (gr < nrows) {
            if (jb.inF32) {
                const float* fin = (const float*)jb.in + (size_t)gr * jb.ldi + c * 8;
                float4 f0 = ((const float4*)fin)[0];
                float4 f1 = ((const float4*)fin)[1];
                v[0] = (f16)f0.x; v[1] = (f16)f0.y; v[2] = (f16)f0.z; v[3] = (f16)f0.w;
                v[4] = (f16)f1.x; v[5] = (f16)f1.y; v[6] = (f16)f1.z; v[7] = (f16)f1.w;
            } else {
                v = *(const half8*)((const f16*)jb.in + (size_t)gr * jb.ldi + c * 8);
            }
        }
        *(half8*)((char*)Xl + r * 256 + ((c * 16) ^ ((r & 7) << 4))) = v;
    }
    // stage W (128 rows x 16 chunks, swizzled)
#pragma unroll
    for (int it = 0; it < 8; ++it) {
        int idx = t + it * 256;
        int r = idx >> 4, c = idx & 15;
        half8 v = *(const half8*)(jb.Wt + (size_t)r * 128 + c * 8);
        *(half8*)((char*)Wl + r * 256 + ((c * 16) ^ ((r & 7) << 4))) = v;
    }
    __syncthreads();

    const int w = t >> 6, l = t & 63;
    const int lr = l & 15;
    const int lk = l >> 4;
    const int arow = w * 16 + lr;
    const int axor = (arow & 7) << 4;
    const int bxor = (lr & 7) << 4;

    f32x4 acc[8];
#pragma unroll
    for (int tn = 0; tn < 8; ++tn)
#pragma unroll
        for (int i = 0; i < 4; ++i) acc[tn][i] = 0.f;

#pragma unroll
    for (int ks = 0; ks < 4; ++ks) {
        int koff = (ks * 4 + lk) * 16;
        half8 a = *(const half8*)((const char*)Xl + arow * 256 + (koff ^ axor));
#pragma unroll
        for (int tn = 0; tn < 8; ++tn) {
            int oc = tn * 16 + lr;
            half8 b = *(const half8*)((const char*)Wl + oc * 256 + (koff ^ bxor));
            acc[tn] = __builtin_amdgcn_mfma_f32_16x16x32_f16(a, b, acc[tn], 0, 0, 0);
        }
    }

    const int rbase = row0 + w * 16 + (lk << 2);
    float brs[4];
#pragma unroll
    for (int i = 0; i < 4; ++i)
        brs[i] = jb.rowscale ? ((rbase + i < nrows) ? jb.rowscale[rbase + i] : 0.f) : 1.0f;
    float bsv[8];
#pragma unroll
    for (int tn = 0; tn < 8; ++tn) bsv[tn] = jb.bias[tn * 16 + lr];

    // stage1 epilogue: h = relu(acc + brs*bias) -> global (optional) + Xl writeback (own rows)
#pragma unroll
    for (int tn = 0; tn < 8; ++tn)
#pragma unroll
        for (int i = 0; i < 4; ++i) {
            f16 v = (f16)fmaxf(acc[tn][i] + brs[i] * bsv[tn], 0.f);
            int lrow = w * 16 + (lk << 2) + i;
            int col = tn * 16 + lr;
            int byte = lrow * 256 + (((col >> 3) * 16) ^ ((lrow & 7) << 4)) + (col & 7) * 2;
            *(f16*)((char*)Xl + byte) = v;
            int gr = rbase + i;
            if (jb.writeOut && gr < nrows) jb.out[(size_t)gr * jb.ldo + col] = v;
        }

    // projection stages: re-stage W, MFMA from LDS-resident h
    for (int p = 0; p < jb.nproj; ++p) {
        Proj pr = jb.proj[p];
        __syncthreads();  // all waves done reading Wl
#pragma unroll
        for (int it = 0; it < 8; ++it) {
            int idx = t + it * 256;
            int r = idx >> 4, c = idx & 15;
            half8 v = *(const half8*)(pr.Wt + (size_t)r * 128 + c * 8);
            *(half8*)((char*)Wl + r * 256 + ((c * 16) ^ ((r & 7) << 4))) = v;
        }
        __syncthreads();  // Wl ready; also orders the Xl writebacks

#pragma unroll
        for (int tn = 0; tn < 8; ++tn)
#pragma unroll
            for (int i = 0; i < 4; ++i) acc[tn][i] = 0.f;
#pragma unroll
        for (int ks = 0; ks < 4; ++ks) {
            int koff = (ks * 4 + lk) * 16;
            half8 a = *(const half8*)((const char*)Xl + arow * 256 + (koff ^ axor));
#pragma unroll
            for (int tn = 0; tn < 8; ++tn) {
                int oc = tn * 16 + lr;
                half8 b = *(const half8*)((const char*)Wl + oc * 256 + (koff ^ bxor));
                acc[tn] = __builtin_amdgcn_mfma_f32_16x16x32_f16(a, b, acc[tn], 0, 0, 0);
            }
        }
        float bp[8];
#pragma unroll
        for (int tn = 0; tn < 8; ++tn) bp[tn] = pr.bias[tn * 16 + lr];
#pragma unroll
        for (int tn = 0; tn < 8; ++tn)
#pragma unroll
            for (int i = 0; i < 4; ++i) {
                int gr = rbase + i;
                if (gr < nrows) pr.out[(size_t)gr * pr.ldo + tn * 16 + lr] = (f16)(acc[tn][i] + bp[tn]);
            }
    }

    // final stage: logits = h @ W2 + b2 -> log_softmax -> fout
    if (jb.doFinal) {
        __syncthreads();
#pragma unroll
        for (int it = 0; it < 4; ++it) {  // W2t: 64 rows x 16 chunks
            int idx = t + it * 256;
            int r = idx >> 4, c = idx & 15;
            half8 v = *(const half8*)(jb.Wt2 + (size_t)r * 128 + c * 8);
            *(half8*)((char*)Wl + r * 256 + ((c * 16) ^ ((r & 7) << 4))) = v;
        }
        __syncthreads();

        f32x4 acc2[4];
#pragma unroll
        for (int tn = 0; tn < 4; ++tn)
#pragma unroll
            for (int i = 0; i < 4; ++i) acc2[tn][i] = 0.f;
#pragma unroll
        for (int ks = 0; ks < 4; ++ks) {
            int koff = (ks * 4 + lk) * 16;
            half8 a = *(const half8*)((const char*)Xl + arow * 256 + (koff ^ axor));
#pragma unroll
            for (int tn = 0; tn < 4; ++tn) {
                int oc = tn * 16 + lr;
                half8 b = *(const half8*)((const char*)Wl + oc * 256 + (koff ^ bxor));
                acc2[tn] = __builtin_amdgcn_mfma_f32_16x16x32_f16(a, b, acc2[tn], 0, 0, 0);
            }
        }
        float bs2[4];
#pragma unroll
        for (int tn = 0; tn < 4; ++tn) bs2[tn] = jb.bias2[tn * 16 + lr];
#pragma unroll
        for (int i = 0; i < 4; ++i) {
            float lg[4];
#pragma unroll
            for (int tn = 0; tn < 4; ++tn) lg[tn] = acc2[tn][i] + bs2[tn];
            float m = fmaxf(fmaxf(lg[0], lg[1]), fmaxf(lg[2], lg[3]));
#pragma unroll
            for (int sft = 1; sft <= 8; sft <<= 1) m = fmaxf(m, __shfl_xor(m, sft));
            float den = 0.f;
#pragma unroll
            for (int tn = 0; tn < 4; ++tn) den += __expf(lg[tn] - m);
#pragma unroll
            for (int sft = 1; sft <= 8; sft <<= 1) den += __shfl_xor(den, sft);
            float lden = logf(den);
            int gr = rbase + i;
            if (gr < nrows) {
                float* op = jb.fout + (size_t)gr * 64;
#pragma unroll
                for (int tn = 0; tn < 4; ++tn) op[tn * 16 + lr] = lg[tn] - m - lden;
            }
        }
    }
}

// ---------------- layer-1 GCN aggregation, quarter-wave (R9 structure, new pack layout) ----------------
__global__ __launch_bounds__(256) void sgather5(
    const int* __restrict__ rowptr, const int* __restrict__ esorted,
    const float* __restrict__ dinv,
    const f16* __restrict__ pack, f16* __restrict__ Sh, float* __restrict__ srow) {
    int d = (blockIdx.x * 256 + threadIdx.x) >> 6;
    int lam = threadIdx.x & 63;
    int qe = lam >> 4, le = lam & 15;
    if (d >= NN) return;
    int i0 = rowptr[d], nE = rowptr[d + 1] - i0 + 1;  // + self-loop (j == nE-1); j >= nE: w=0
    float dvd = dinv[d];
    float u[8];
#pragma unroll
    for (int i = 0; i < 8; ++i) u[i] = 0.f;
    float ssum = 0.f;

    auto ldb = [&](int b, float& w, half8& h) {
        int j = b + qe;
        int s = (j < nE - 1) ? esorted[i0 + j] : d;
        w = (j < nE) ? dinv[s] : 0.f;
        h = *(const half8*)(pack + (size_t)s * PST + H0 + le * 8);
    };
    auto cmp = [&](float w, const half8& h) {
#pragma unroll
        for (int i = 0; i < 8; ++i) u[i] = fmaf(w, (float)h[i], u[i]);
        ssum += w;
    };

    float wA, wB; half8 hA, hB;
    ldb(0, wA, hA);
    for (int b = 0; b < nE; b += 8) {
        ldb(b + 4, wB, hB);
        cmp(wA, hA);
        ldb(b + 8, wA, hA);
        cmp(wB, hB);
    }
#pragma unroll
    for (int i = 0; i < 8; ++i) {
        u[i] += __shfl_xor(u[i], 16);
        u[i] += __shfl_xor(u[i], 32);
    }
    ssum += __shfl_xor(ssum, 16);
    ssum += __shfl_xor(ssum, 32);
    if (qe == 0) {
        half8 o;
#pragma unroll
        for (int i = 0; i < 8; ++i) o[i] = (f16)(dvd * u[i]);
        *(half8*)(Sh + (size_t)d * 128 + le * 8) = o;
        if (le == 0) srow[d] = dvd * ssum;
    }
}

// ---------------- node attention (deferred V), quarter-wave (R9 structure) ----------------
// KOFF: k region offset in pack for this layer; h levels at H0
template<int L, int KOFF>
__global__ __launch_bounds__(256) void node_attn8(
    const int* __restrict__ rowptr, const int* __restrict__ esorted,
    const float* __restrict__ dinv,
    const f16* __restrict__ qh, const f16* __restrict__ pack,
    f16* __restrict__ uh) {
    int d = (blockIdx.x * 256 + threadIdx.x) >> 6;
    int lam = threadIdx.x & 63;
    int qe = lam >> 4, le = lam & 15;
    if (d >= NN) return;
    int i0 = rowptr[d], nE = rowptr[d + 1] - i0 + 1;  // self-loop at j == nE-1; j >= nE: w=0
    float dvd = dinv[d];
    half8 q8 = *(const half8*)(qh + (size_t)d * 128 + le * 8);
    const f16x2* qp = (const f16x2*)&q8;
    float u[8];
#pragma unroll
    for (int i = 0; i < 8; ++i) u[i] = 0.f;

    auto ldb = [&](int b, float& w, half8 (&k)[L], half8 (&h)[L]) {
        int j = b + qe;
        int s = (j < nE - 1) ? esorted[i0 + j] : d;
        w = (j < nE) ? dinv[s] : 0.f;
        const f16* bp = pack + (size_t)s * PST + le * 8;
#pragma unroll
        for (int l = 0; l < L; ++l) {
            k[l] = *(const half8*)(bp + KOFF + l * 128);
            h[l] = *(const half8*)(bp + H0 + l * 128);
        }
    };
    auto cmp = [&](float w, const half8 (&k)[L], const half8 (&h)[L]) {
        float sc[L];
#pragma unroll
        for (int l = 0; l < L; ++l) {
            const f16x2* kp = (const f16x2*)&k[l];
            float p = 0.f;
#pragma unroll
            for (int i = 0; i < 4; ++i) p = fdot2(qp[i], kp[i], p);
            p += __shfl_xor(p, 1);  // partner lane holds the head's other 8 channels
            sc[l] = p * 0.25f;      // 1/sqrt(16)
        }
        float m = sc[0];
#pragma unroll
        for (int l = 1; l < L; ++l) m = fmaxf(m, sc[l]);
        float den = 0.f;
#pragma unroll
        for (int l = 0; l < L; ++l) { sc[l] = __expf(sc[l] - m); den += sc[l]; }
        float wg = w * __builtin_amdgcn_rcpf(den);
#pragma unroll
        for (int l = 0; l < L; ++l) {
            float a = sc[l] * wg;
#pragma unroll
            for (int i = 0; i < 8; ++i) u[i] = fmaf(a, (float)h[l][i], u[i]);
        }
    };

    float wA, wB; half8 kA[L], hA[L], kB[L], hB[L];
    ldb(0, wA, kA, hA);
    for (int b = 0; b < nE; b += 8) {
        ldb(b + 4, wB, kB, hB);
        cmp(wA, kA, hA);
        ldb(b + 8, wA, kA, hA);
        cmp(wB, kB, hB);
    }
#pragma unroll
    for (int i = 0; i < 8; ++i) {
        u[i] += __shfl_xor(u[i], 16);
        u[i] += __shfl_xor(u[i], 32);
    }
    if (qe == 0) {
        half8 o;
#pragma unroll
        for (int i = 0; i < 8; ++i) o[i] = (f16)(dvd * u[i]);
        *(half8*)(uh + (size_t)d * 128 + le * 8) = o;
    }
}

extern "C" void kernel_launch(void* const* d_in, const int* in_sizes, int n_in,
                              void* d_out, int out_size, void* d_ws, size_t ws_size,
                              hipStream_t stream) {
    (void)in_sizes; (void)n_in; (void)out_size; (void)ws_size;
    const float* x  = (const float*)d_in[0];
    const int*   ei = (const int*)d_in[1];
    const float* W1 = (const float*)d_in[2];
    const float* b1 = (const float*)d_in[3];
    const float* Wq = (const float*)d_in[4];
    const float* bq = (const float*)d_in[5];
    const float* Wk = (const float*)d_in[6];
    const float* bk = (const float*)d_in[7];
    const float* Wv = (const float*)d_in[8];
    const float* bv = (const float*)d_in[9];
    const float* W2 = (const float*)d_in[10];
    const float* b2 = (const float*)d_in[11];
    float* out = (float*)d_out;

    // workspace layout (4-byte words)
    int*    cnt     = (int*)d_ws;                  // 16384 (zeroed by prep)
    int*    rowfill = cnt + 16384;                 // 16384 (init by scan)
    int*    rowptr  = rowfill + 16384;             // 16384 (NN+1)
    int*    esorted = rowptr + 16384;              // 163840
    float*  dinv    = (float*)(esorted + 163840);  // 16384
    float*  srow    = dinv + 16384;                // 16384 (written by sgather, no zero needed)
    f16*    pack    = (f16*)(srow + 16384);        // NN x 1024 halves
    f16*    Sh      = pack + (size_t)NN * PST;     // N128
    f16*    qh      = Sh + N128;                   // N128
    f16*    uh      = qh + N128;                   // N128
    f16*    Wt      = uh + N128;                   // 9 x 16384

    auto WT = [&](int m) { return Wt + (size_t)m * 16384; };
    // slots: 0=W1, 1..3=Wv[0..2], 4=W2, 5=Wq[1], 6=Wq[2], 7=Wk[1], 8=Wk[2]

    prep_fused<<<25, 256, 0, stream>>>(W1, Wq, Wk, Wv, W2, Wt, (int4*)cnt);
    cnt_count<<<(EE + 255) / 256, 256, 0, stream>>>(ei + EE, cnt);
    scan_rowptr<<<1, 256, 0, stream>>>(cnt, rowptr, rowfill, dinv);
    scatter_edges<<<(EE + 255) / 256, 256, 0, stream>>>(ei, rowfill, esorted);

    const int gx = (NN + 63) / 64;  // 157
    const int nblocks = (NN * 64 + 255) / 256;

    {   // D1: h0 = relu(x@W1+b1) -> pack[H0]; proj k2_0 = h0@Wk[1]+bk[1]; k3_0 = h0@Wk[2]+bk[2]
        FJob j{};
        j.in = x; j.inF32 = 1; j.ldi = HID;
        j.Wt = WT(0); j.bias = b1; j.rowscale = nullptr;
        j.out = pack + H0; j.ldo = PST; j.writeOut = 1;
        j.nproj = 2;
        j.proj[0] = {WT(7), bk + HID,     pack + 0,   PST};
        j.proj[1] = {WT(8), bk + 2 * HID, pack + 256, PST};
        gemm_fused<<<gx, 256, 0, stream>>>(j, NN);
    }

    // layer 1 (L=1: softmax identity -> GCN with deferred Wv[0])
    sgather5<<<nblocks, 256, 0, stream>>>(rowptr, esorted, dinv, pack, Sh, srow);

    {   // D2: h1 = relu(S@Wv[0]+srow*bv[0]) -> pack[H0+128]; proj q2=h1@Wq[1]+bq[1]; k2_1; k3_1
        FJob j{};
        j.in = Sh; j.inF32 = 0; j.ldi = HID;
        j.Wt = WT(1); j.bias = bv; j.rowscale = srow;
        j.out = pack + H0 + 128; j.ldo = PST; j.writeOut = 1;
        j.nproj = 3;
        j.proj[0] = {WT(5), bq + HID,     qh,         HID};
        j.proj[1] = {WT(7), bk + HID,     pack + 128, PST};
        j.proj[2] = {WT(8), bk + 2 * HID, pack + 384, PST};
        gemm_fused<<<gx, 256, 0, stream>>>(j, NN);
    }

    node_attn8<2, 0><<<nblocks, 256, 0, stream>>>(rowptr, esorted, dinv, qh, pack, uh);

    {   // D3: h2 = relu(u@Wv[1]+srow*bv[1]) -> pack[H0+256]; proj q3=h2@Wq[2]+bq[2]; k3_2
        FJob j{};
        j.in = uh; j.inF32 = 0; j.ldi = HID;
        j.Wt = WT(2); j.bias = bv + HID; j.rowscale = srow;
        j.out = pack + H0 + 256; j.ldo = PST; j.writeOut = 1;
        j.nproj = 2;
        j.proj[0] = {WT(6), bq + 2 * HID, qh,         HID};
        j.proj[1] = {WT(8), bk + 2 * HID, pack + 512, PST};
        gemm_fused<<<gx, 256, 0, stream>>>(j, NN);
    }

    node_attn8<3, 256><<<nblocks, 256, 0, stream>>>(rowptr, esorted, dinv, qh, pack, uh);

    {   // D4: h3 = relu(u@Wv[2]+srow*bv[2]) (LDS only); out = log_softmax(h3@W2+b2)
        FJob j{};
        j.in = uh; j.inF32 = 0; j.ldi = HID;
        j.Wt = WT(3); j.bias = bv + 2 * HID; j.rowscale = srow;
        j.out = nullptr; j.ldo = HID; j.writeOut = 0;
        j.nproj = 0;
        j.doFinal = 1; j.Wt2 = WT(4); j.bias2 = b2; j.fout = out;
        gemm_fused<<<gx, 256, 0, stream>>>(j, NN);
    }
}

// Round 13
// 175.613 us; speedup vs baseline: 1.0250x; 1.0250x over previous
//
#include <hip/hip_runtime.h>
#include <hip/hip_fp16.h>
#include <math.h>

#define NN 10000
#define EE 160000
#define HID 128
constexpr int N128 = NN * HID;
constexpr int PSTR = 768;  // pack stride in halves: [k0 k1 k2 | h0 h1 h2]
constexpr int HOFF = 384;  // h region offset in pack (halves)

typedef _Float16 f16;
typedef f16 half8 __attribute__((ext_vector_type(8)));
typedef f16 f16x2 __attribute__((ext_vector_type(2)));
typedef float f32x4 __attribute__((ext_vector_type(4)));

#if __has_builtin(__builtin_amdgcn_fdot2)
__device__ inline float fdot2(f16x2 a, f16x2 b, float c) { return __builtin_amdgcn_fdot2(a, b, c, false); }
#else
__device__ inline float fdot2(f16x2 a, f16x2 b, float c) {
    return fmaf((float)a[0], (float)b[0], fmaf((float)a[1], (float)b[1], c));
}
#endif

// ---------------- zero cnt (16384 ints = 4096 int4 = 16 blocks) ----------------
__global__ __launch_bounds__(256) void zero_cnt(int4* __restrict__ p) {
    p[blockIdx.x * 256 + threadIdx.x] = make_int4(0, 0, 0, 0);
}

// ---------------- fused: weight prep (blocks 0..10) + degree count (blocks 11..635) ----------------
__global__ __launch_bounds__(256) void prep_cnt(const float* __restrict__ W1, const float* __restrict__ Wq,
                                                const float* __restrict__ Wk, const float* __restrict__ Wv,
                                                const float* __restrict__ W2, f16* __restrict__ Wt,
                                                const int* __restrict__ dst, int* __restrict__ cnt) {
    int b = blockIdx.x;  // 0=W1, 1..3=Wq[l], 4..6=Wk[l], 7..9=Wv[l], 10=W2, 11.. = cnt_count
    int t = threadIdx.x;
    if (b >= 11) {
        int e = (b - 11) * 256 + t;
        if (e < EE) atomicAdd(&cnt[dst[e]], 1);
        return;
    }
    f16* dstw = Wt + (size_t)b * 16384;
    if (b == 10) {
        int oc = t & 63, k0 = (t >> 6) * 32;
        for (int kk = 0; kk < 32; ++kk) {
            int k = k0 + kk;
            dstw[oc * 128 + k] = (f16)W2[(size_t)k * 64 + oc];
        }
        return;
    }
    const float* src = (b == 0) ? W1
                     : (b < 4)  ? Wq + (size_t)(b - 1) * 16384
                     : (b < 7)  ? Wk + (size_t)(b - 4) * 16384
                                : Wv + (size_t)(b - 7) * 16384;
    int oc = t >> 1;
    int k0 = (t & 1) * 64;
    for (int kk = 0; kk < 64; ++kk) {
        int k = k0 + kk;
        dstw[oc * 128 + k] = (f16)src[k * 128 + oc];
    }
}

// ---------------- single-block scan -> rowptr + rowfill cursors + dinv ----------------
__global__ __launch_bounds__(256) void scan_rowptr(const int* __restrict__ cnt, int* __restrict__ rowptr,
                                                   int* __restrict__ rowfill, float* __restrict__ dinv) {
    __shared__ int part[256];
    const int PER = (NN + 255) / 256;  // 40
    int t = threadIdx.x;
    int base = t * PER;
    int sum = 0;
    for (int i = 0; i < PER; ++i) {
        int idx = base + i;
        if (idx < NN) {
            int c = cnt[idx];
            sum += c;
            dinv[idx] = rsqrtf((float)c + 1.0f);  // +1 self-loop
        }
    }
    part[t] = sum;
    __syncthreads();
    for (int ofs = 1; ofs < 256; ofs <<= 1) {
        int v = (t >= ofs) ? part[t - ofs] : 0;
        __syncthreads();
        part[t] += v;
        __syncthreads();
    }
    int run = (t > 0) ? part[t - 1] : 0;
    for (int i = 0; i < PER; ++i) {
        int idx = base + i;
        if (idx <= NN) rowptr[idx] = run;
        if (idx < NN) { rowfill[idx] = run; run += cnt[idx]; }
    }
}

__global__ __launch_bounds__(256) void scatter_edges(const int* __restrict__ ei,
                                                     int* __restrict__ rowfill,
                                                     int* __restrict__ esorted) {
    int e = blockIdx.x * 256 + threadIdx.x;
    if (e < EE) {
        int s = ei[e], d = ei[EE + e];
        int pos = atomicAdd(&rowfill[d], 1);
        esorted[pos] = s;
    }
}

// ---------------- MFMA GEMM, NTN = number of 16-col output tiles (8 = 128 cols, 4 = 64 cols) ----------------
// mode 0=f32 out, 1=f16+relu, 2=f16 raw, 3(NTN=8 only)=fused final: relu -> @W2t -> +b2 -> log_softmax -> f32
struct GJob {
    const void* in; const f16* Wt; const float* bias; const float* rowscale;
    void* out; int ldi; int ldo; int mode; int inF32;
    const f16* Wt2; const float* bias2;
};
struct GJobs { GJob j[7]; };

template<int NTN>
__global__ __launch_bounds__(256) void gemm_mfma(GJobs jobs, int nrows) {
    const GJob jb = jobs.j[blockIdx.y];
    __shared__ f16 Xl[64 * 128];
    __shared__ f16 Wl[NTN * 16 * 128];
    const int t = threadIdx.x;
    const int row0 = blockIdx.x * 64;

    half8 zero8;
#pragma unroll
    for (int z = 0; z < 8; ++z) zero8[z] = (f16)0.f;

#pragma unroll
    for (int it = 0; it < 4; ++it) {
        int idx = t + it * 256;
        int r = idx >> 4, c = idx & 15;
        int gr = row0 + r;
        half8 v = zero8;
        if (gr < nrows) {
            if (jb.inF32) {
                const float* fin = (const float*)jb.in + (size_t)gr * jb.ldi + c * 8;
                float4 f0 = ((const float4*)fin)[0];
                float4 f1 = ((const float4*)fin)[1];
                v[0] = (f16)f0.x; v[1] = (f16)f0.y; v[2] = (f16)f0.z; v[3] = (f16)f0.w;
                v[4] = (f16)f1.x; v[5] = (f16)f1.y; v[6] = (f16)f1.z; v[7] = (f16)f1.w;
            } else {
                v = *(const half8*)((const f16*)jb.in + (size_t)gr * jb.ldi + c * 8);
            }
        }
        *(half8*)((char*)Xl + r * 256 + ((c * 16) ^ ((r & 7) << 4))) = v;
    }
#pragma unroll
    for (int it = 0; it < NTN; ++it) {  // NTN*16 rows of Wt
        int idx = t + it * 256;
        int r = idx >> 4, c = idx & 15;
        half8 v = *(const half8*)(jb.Wt + (size_t)r * 128 + c * 8);
        *(half8*)((char*)Wl + r * 256 + ((c * 16) ^ ((r & 7) << 4))) = v;
    }
    __syncthreads();

    const int w = t >> 6, l = t & 63;
    const int lr = l & 15;
    const int lk = l >> 4;

    f32x4 acc[NTN];
#pragma unroll
    for (int tn = 0; tn < NTN; ++tn)
#pragma unroll
        for (int i = 0; i < 4; ++i) acc[tn][i] = 0.f;

    const int arow = w * 16 + lr;
    const int axor = (arow & 7) << 4;
    const int bxor = (lr & 7) << 4;

#pragma unroll
    for (int ks = 0; ks < 4; ++ks) {
        int koff = (ks * 4 + lk) * 16;
        half8 a = *(const half8*)((const char*)Xl + arow * 256 + (koff ^ axor));
#pragma unroll
        for (int tn = 0; tn < NTN; ++tn) {
            int oc = tn * 16 + lr;
            half8 b = *(const half8*)((const char*)Wl + oc * 256 + (koff ^ bxor));
            acc[tn] = __builtin_amdgcn_mfma_f32_16x16x32_f16(a, b, acc[tn], 0, 0, 0);
        }
    }

    const int rbase = row0 + w * 16 + (lk << 2);
    float brs[4];
#pragma unroll
    for (int i = 0; i < 4; ++i)
        brs[i] = jb.rowscale ? ((rbase + i < nrows) ? jb.rowscale[rbase + i] : 0.f) : 1.0f;
    float bsv[NTN];
#pragma unroll
    for (int tn = 0; tn < NTN; ++tn) bsv[tn] = jb.bias[tn * 16 + lr];

    if (jb.mode == 0) {
        float* op = (float*)jb.out;
#pragma unroll
        for (int tn = 0; tn < NTN; ++tn)
#pragma unroll
            for (int i = 0; i < 4; ++i) {
                int gr = rbase + i;
                if (gr < nrows) op[(size_t)gr * jb.ldo + tn * 16 + lr] = acc[tn][i] + brs[i] * bsv[tn];
            }
    } else if (jb.mode == 1) {
        f16* op = (f16*)jb.out;
#pragma unroll
        for (int tn = 0; tn < NTN; ++tn)
#pragma unroll
            for (int i = 0; i < 4; ++i) {
                int gr = rbase + i;
                if (gr < nrows) op[(size_t)gr * jb.ldo + tn * 16 + lr] = (f16)fmaxf(acc[tn][i] + brs[i] * bsv[tn], 0.f);
            }
    } else if (jb.mode == 2) {
        f16* op = (f16*)jb.out;
#pragma unroll
        for (int tn = 0; tn < NTN; ++tn)
#pragma unroll
            for (int i = 0; i < 4; ++i) {
                int gr = rbase + i;
                if (gr < nrows) op[(size_t)gr * jb.ldo + tn * 16 + lr] = (f16)(acc[tn][i] + brs[i] * bsv[tn]);
            }
    } else if constexpr (NTN == 8) {
        // mode 3: h3 = relu(acc + brs*bsv) -> Xl (swizzled); stage W2t -> Wl; MFMA vs W2t; +b2; log_softmax
        __syncthreads();  // everyone done reading Xl/Wl
#pragma unroll
        for (int tn = 0; tn < 8; ++tn)
#pragma unroll
            for (int i = 0; i < 4; ++i) {
                f16 v = (f16)fmaxf(acc[tn][i] + brs[i] * bsv[tn], 0.f);
                int lrow = w * 16 + (lk << 2) + i;
                int col = tn * 16 + lr;
                int byte = lrow * 256 + ((((col >> 3) * 16) ^ ((lrow & 7) << 4))) + (col & 7) * 2;
                *(f16*)((char*)Xl + byte) = v;
            }
#pragma unroll
        for (int it = 0; it < 4; ++it) {  // W2t: 64 rows x 16 chunks
            int idx = t + it * 256;
            int r = idx >> 4, c = idx & 15;
            half8 v = *(const half8*)(jb.Wt2 + (size_t)r * 128 + c * 8);
            *(half8*)((char*)Wl + r * 256 + ((c * 16) ^ ((r & 7) << 4))) = v;
        }
        __syncthreads();

        f32x4 acc2[4];
#pragma unroll
        for (int tn = 0; tn < 4; ++tn)
#pragma unroll
            for (int i = 0; i < 4; ++i) acc2[tn][i] = 0.f;
#pragma unroll
        for (int ks = 0; ks < 4; ++ks) {
            int koff = (ks * 4 + lk) * 16;
            half8 a = *(const half8*)((const char*)Xl + arow * 256 + (koff ^ axor));
#pragma unroll
            for (int tn = 0; tn < 4; ++tn) {
                int oc = tn * 16 + lr;
                half8 b = *(const half8*)((const char*)Wl + oc * 256 + (koff ^ bxor));
                acc2[tn] = __builtin_amdgcn_mfma_f32_16x16x32_f16(a, b, acc2[tn], 0, 0, 0);
            }
        }
        float bs2[4];
#pragma unroll
        for (int tn = 0; tn < 4; ++tn) bs2[tn] = jb.bias2[tn * 16 + lr];
#pragma unroll
        for (int i = 0; i < 4; ++i) {
            float lg[4];
#pragma unroll
            for (int tn = 0; tn < 4; ++tn) lg[tn] = acc2[tn][i] + bs2[tn];
            float m = fmaxf(fmaxf(lg[0], lg[1]), fmaxf(lg[2], lg[3]));
#pragma unroll
            for (int sft = 1; sft <= 8; sft <<= 1) m = fmaxf(m, __shfl_xor(m, sft));
            float den = 0.f;
#pragma unroll
            for (int tn = 0; tn < 4; ++tn) den += __expf(lg[tn] - m);
#pragma unroll
            for (int sft = 1; sft <= 8; sft <<= 1) den += __shfl_xor(den, sft);
            float lden = logf(den);
            int gr = rbase + i;
            if (gr < nrows) {
                float* op = (float*)jb.out + (size_t)gr * jb.ldo;
#pragma unroll
                for (int tn = 0; tn < 4; ++tn) op[tn * 16 + lr] = lg[tn] - m - lden;
            }
        }
    }
}

// ---------------- layer-1 GCN aggregation, quarter-wave (4 edges/wave) ----------------
__global__ __launch_bounds__(256) void sgather5(
    const int* __restrict__ rowptr, const int* __restrict__ esorted,
    const float* __restrict__ dinv,
    const f16* __restrict__ hsrc /* pack + HOFF */, f16* __restrict__ Sh, float* __restrict__ srow) {
    int d = (blockIdx.x * 256 + threadIdx.x) >> 6;
    int lam = threadIdx.x & 63;
    int qe = lam >> 4, le = lam & 15;
    if (d >= NN) return;
    int i0 = rowptr[d], nE = rowptr[d + 1] - i0 + 1;  // + self-loop (j == nE-1); j >= nE: w=0
    float dvd = dinv[d];
    float u[8];
#pragma unroll
    for (int i = 0; i < 8; ++i) u[i] = 0.f;
    float ssum = 0.f;

    auto ldb = [&](int b, float& w, half8& h) {
        int j = b + qe;
        int s = (j < nE - 1) ? esorted[i0 + j] : d;
        w = (j < nE) ? dinv[s] : 0.f;
        h = *(const half8*)(hsrc + (size_t)s * PSTR + le * 8);
    };
    auto cmp = [&](float w, const half8& h) {
#pragma unroll
        for (int i = 0; i < 8; ++i) u[i] = fmaf(w, (float)h[i], u[i]);
        ssum += w;
    };

    float wA, wB; half8 hA, hB;
    ldb(0, wA, hA);
    for (int b = 0; b < nE; b += 8) {
        ldb(b + 4, wB, hB);
        cmp(wA, hA);
        ldb(b + 8, wA, hA);
        cmp(wB, hB);
    }
#pragma unroll
    for (int i = 0; i < 8; ++i) {
        u[i] += __shfl_xor(u[i], 16);
        u[i] += __shfl_xor(u[i], 32);
    }
    ssum += __shfl_xor(ssum, 16);
    ssum += __shfl_xor(ssum, 32);
    if (qe == 0) {
        half8 o;
#pragma unroll
        for (int i = 0; i < 8; ++i) o[i] = (f16)(dvd * u[i]);
        *(half8*)(Sh + (size_t)d * 128 + le * 8) = o;
        if (le == 0) srow[d] = dvd * ssum;
    }
}

// ---------------- node attention (deferred V), quarter-wave: 4 edges/wave, 16B/lane ----------------
// lane: qe = lam>>4 (edge slot), le = lam&15 (channels [8*le,8*le+8), head = le>>1)
template<int L>
__global__ __launch_bounds__(256) void node_attn5(
    const int* __restrict__ rowptr, const int* __restrict__ esorted,
    const float* __restrict__ dinv,
    const f16* __restrict__ qh, const f16* __restrict__ pack,
    f16* __restrict__ uh) {
    int d = (blockIdx.x * 256 + threadIdx.x) >> 6;
    int lam = threadIdx.x & 63;
    int qe = lam >> 4, le = lam & 15;
    if (d >= NN) return;
    int i0 = rowptr[d], nE = rowptr[d + 1] - i0 + 1;  // self-loop at j == nE-1; j >= nE: w=0
    float dvd = dinv[d];
    half8 q8 = *(const half8*)(qh + (size_t)d * 128 + le * 8);
    const f16x2* qp = (const f16x2*)&q8;
    float u[8];
#pragma unroll
    for (int i = 0; i < 8; ++i) u[i] = 0.f;

    auto ldb = [&](int b, float& w, half8 (&k)[L], half8 (&h)[L]) {
        int j = b + qe;
        int s = (j < nE - 1) ? esorted[i0 + j] : d;
        w = (j < nE) ? dinv[s] : 0.f;
        const f16* bp = pack + (size_t)s * PSTR + le * 8;
#pragma unroll
        for (int l = 0; l < L; ++l) {
            k[l] = *(const half8*)(bp + l * 128);
            h[l] = *(const half8*)(bp + HOFF + l * 128);
        }
    };
    auto cmp = [&](float w, const half8 (&k)[L], const half8 (&h)[L]) {
        float sc[L];
#pragma unroll
        for (int l = 0; l < L; ++l) {
            const f16x2* kp = (const f16x2*)&k[l];
            float p = 0.f;
#pragma unroll
            for (int i = 0; i < 4; ++i) p = fdot2(qp[i], kp[i], p);
            p += __shfl_xor(p, 1);  // partner lane holds the head's other 8 channels
            sc[l] = p * 0.25f;      // 1/sqrt(16)
        }
        float m = sc[0];
#pragma unroll
        for (int l = 1; l < L; ++l) m = fmaxf(m, sc[l]);
        float den = 0.f;
#pragma unroll
        for (int l = 0; l < L; ++l) { sc[l] = __expf(sc[l] - m); den += sc[l]; }
        float wg = w * __builtin_amdgcn_rcpf(den);
#pragma unroll
        for (int l = 0; l < L; ++l) {
            float a = sc[l] * wg;
#pragma unroll
            for (int i = 0; i < 8; ++i) u[i] = fmaf(a, (float)h[l][i], u[i]);
        }
    };

    float wA, wB; half8 kA[L], hA[L], kB[L], hB[L];
    ldb(0, wA, kA, hA);
    for (int b = 0; b < nE; b += 8) {
        ldb(b + 4, wB, kB, hB);
        cmp(wA, kA, hA);
        ldb(b + 8, wA, kA, hA);
        cmp(wB, kB, hB);
    }
#pragma unroll
    for (int i = 0; i < 8; ++i) {
        u[i] += __shfl_xor(u[i], 16);
        u[i] += __shfl_xor(u[i], 32);
    }
    if (qe == 0) {
        half8 o;
#pragma unroll
        for (int i = 0; i < 8; ++i) o[i] = (f16)(dvd * u[i]);
        *(half8*)(uh + (size_t)d * 128 + le * 8) = o;
    }
}

extern "C" void kernel_launch(void* const* d_in, const int* in_sizes, int n_in,
                              void* d_out, int out_size, void* d_ws, size_t ws_size,
                              hipStream_t stream) {
    (void)in_sizes; (void)n_in; (void)out_size; (void)ws_size;
    const float* x  = (const float*)d_in[0];
    const int*   ei = (const int*)d_in[1];
    const float* W1 = (const float*)d_in[2];
    const float* b1 = (const float*)d_in[3];
    const float* Wq = (const float*)d_in[4];
    const float* bq = (const float*)d_in[5];
    const float* Wk = (const float*)d_in[6];
    const float* bk = (const float*)d_in[7];
    const float* Wv = (const float*)d_in[8];
    const float* bv = (const float*)d_in[9];
    const float* W2 = (const float*)d_in[10];
    const float* b2 = (const float*)d_in[11];
    float* out = (float*)d_out;

    // workspace layout (4-byte words)
    int*    cnt     = (int*)d_ws;                  // 16384 (zeroed by zero_cnt)
    int*    rowfill = cnt + 16384;                 // 16384 (init by scan)
    int*    rowptr  = rowfill + 16384;             // 16384 (NN+1)
    int*    esorted = rowptr + 16384;              // 163840
    float*  dinv    = (float*)(esorted + 163840);  // 16384
    float*  srow    = dinv + 16384;                // 16384 (fully written by sgather)
    f16*    pack    = (f16*)(srow + 16384);        // NN x 768 halves
    f16*    Sh      = pack + (size_t)NN * PSTR;    // N128
    f16*    qh      = Sh + N128;                   // N128
    f16*    uh      = qh + N128;                   // N128
    f16*    Wt      = uh + N128;                   // 11 x 16384

    zero_cnt<<<16, 256, 0, stream>>>((int4*)cnt);
    prep_cnt<<<11 + (EE + 255) / 256, 256, 0, stream>>>(W1, Wq, Wk, Wv, W2, Wt, ei + EE, cnt);
    scan_rowptr<<<1, 256, 0, stream>>>(cnt, rowptr, rowfill, dinv);
    scatter_edges<<<(EE + 255) / 256, 256, 0, stream>>>(ei, rowfill, esorted);

    const int gx = (NN + 63) / 64;  // 157
    auto WT = [&](int m) { return Wt + (size_t)m * 16384; };  // 0=W1,1..3=Wq,4..6=Wk,7..9=Wv,10=W2
    auto H  = [&](int lev) { return pack + HOFF + lev * 128; };  // h-level base (stride PSTR)
    auto K  = [&](int lev) { return pack + lev * 128; };         // k-level base (stride PSTR)

    {   // D1: h0 = relu(x @ W1 + b1) -> pack (f32 input), column-split into 2 jobs
        GJobs jobs{};
        jobs.j[0] = {x, WT(0),            b1,      nullptr, H(0),      HID, PSTR, 1, 1, nullptr, nullptr};
        jobs.j[1] = {x, WT(0) + 64 * 128, b1 + 64, nullptr, H(0) + 64, HID, PSTR, 1, 1, nullptr, nullptr};
        gemm_mfma<4><<<dim3(gx, 2), 256, 0, stream>>>(jobs, NN);
    }

    const int nblocks = (NN * 64 + 255) / 256;

    // ---- layer 1 (L=1: softmax over 1 level == identity -> GCN, deferred Wv1) ----
    sgather5<<<nblocks, 256, 0, stream>>>(rowptr, esorted, dinv, pack + HOFF, Sh, srow);
    {   // h1 = relu(S @ Wv1 + srow*bv1) -> pack, column-split
        GJobs jobs{};
        jobs.j[0] = {Sh, WT(7),            bv,      srow, H(1),      HID, PSTR, 1, 0, nullptr, nullptr};
        jobs.j[1] = {Sh, WT(7) + 64 * 128, bv + 64, srow, H(1) + 64, HID, PSTR, 1, 0, nullptr, nullptr};
        gemm_mfma<4><<<dim3(gx, 2), 256, 0, stream>>>(jobs, NN);
    }

    // ---- layers 2,3: q/k GEMMs -> attention (aggregate raw h) -> deferred Wv GEMM ----
    for (int l = 1; l < 3; ++l) {
        int L = l + 1;
        GJobs jobs{};
        jobs.j[0] = {H(L - 1), WT(1 + l), bq + l * HID, nullptr, qh, PSTR, HID, 2, 0, nullptr, nullptr};
        for (int lev = 0; lev < L; ++lev)
            jobs.j[1 + lev] = {H(lev), WT(4 + l), bk + l * HID, nullptr, K(lev), PSTR, PSTR, 2, 0, nullptr, nullptr};
        gemm_mfma<8><<<dim3(gx, 1 + L), 256, 0, stream>>>(jobs, NN);

        if (L == 2) node_attn5<2><<<nblocks, 256, 0, stream>>>(rowptr, esorted, dinv, qh, pack, uh);
        if (L == 3) node_attn5<3><<<nblocks, 256, 0, stream>>>(rowptr, esorted, dinv, qh, pack, uh);

        if (L == 2) {
            // h2 = relu(u @ Wv2 + srow*bv2) -> pack, column-split
            GJobs vjob{};
            vjob.j[0] = {uh, WT(8),            bv + HID,      srow, H(2),      HID, PSTR, 1, 0, nullptr, nullptr};
            vjob.j[1] = {uh, WT(8) + 64 * 128, bv + HID + 64, srow, H(2) + 64, HID, PSTR, 1, 0, nullptr, nullptr};
            gemm_mfma<4><<<dim3(gx, 2), 256, 0, stream>>>(vjob, NN);
        } else {
            // fused: h3 = relu(u @ Wv3 + srow*bv3); out = log_softmax(h3 @ W2 + b2)
            GJobs vjob{};
            vjob.j[0] = {uh, WT(9), bv + 2 * HID, srow, out, HID, 64, 3, 0, WT(10), b2};
            gemm_mfma<8><<<dim3(gx, 1), 256, 0, stream>>>(vjob, NN);
        }
    }
}

// Round 15
// 169.223 us; speedup vs baseline: 1.0637x; 1.0378x over previous
//
#include <hip/hip_runtime.h>
#include <hip/hip_fp16.h>
#include <math.h>

#define NN 10000
#define EE 160000
#define HID 128
constexpr int N128 = NN * HID;
constexpr int PSTR = 768;  // pack stride in halves: [k0 k1 k2 | h0 h1 h2]
constexpr int HOFF = 384;  // h region offset in pack (halves)

typedef _Float16 f16;
typedef f16 half8 __attribute__((ext_vector_type(8)));
typedef f16 f16x2 __attribute__((ext_vector_type(2)));
typedef float f32x4 __attribute__((ext_vector_type(4)));

#if __has_builtin(__builtin_amdgcn_fdot2)
__device__ inline float fdot2(f16x2 a, f16x2 b, float c) { return __builtin_amdgcn_fdot2(a, b, c, false); }
#else
__device__ inline float fdot2(f16x2 a, f16x2 b, float c) {
    return fmaf((float)a[0], (float)b[0], fmaf((float)a[1], (float)b[1], c));
}
#endif

// ---------------- degree count (by dst) ----------------
__global__ __launch_bounds__(256) void cnt_count(const int* __restrict__ dst, int* __restrict__ cnt) {
    int e = blockIdx.x * 256 + threadIdx.x;
    if (e < EE) atomicAdd(&cnt[dst[e]], 1);
}

// ---------------- single-block exclusive scan -> rowptr, + dinv fused ----------------
__global__ __launch_bounds__(256) void scan_rowptr(const int* __restrict__ cnt, int* __restrict__ rowptr,
                                                   float* __restrict__ dinv) {
    __shared__ int part[256];
    const int PER = (NN + 255) / 256;  // 40
    int t = threadIdx.x;
    int base = t * PER;
    int sum = 0;
    for (int i = 0; i < PER; ++i) {
        int idx = base + i;
        if (idx < NN) {
            int c = cnt[idx];
            sum += c;
            dinv[idx] = rsqrtf((float)c + 1.0f);  // +1 self-loop
        }
    }
    part[t] = sum;
    __syncthreads();
    for (int ofs = 1; ofs < 256; ofs <<= 1) {
        int v = (t >= ofs) ? part[t - ofs] : 0;
        __syncthreads();
        part[t] += v;
        __syncthreads();
    }
    int run = (t > 0) ? part[t - 1] : 0;
    for (int i = 0; i < PER; ++i) {
        int idx = base + i;
        if (idx <= NN) rowptr[idx] = run;
        if (idx < NN) run += cnt[idx];
    }
}

__global__ __launch_bounds__(256) void scatter_edges(const int* __restrict__ ei,
                                                     const int* __restrict__ rowptr,
                                                     int* __restrict__ fill,
                                                     int* __restrict__ esorted) {
    int e = blockIdx.x * 256 + threadIdx.x;
    if (e < EE) {
        int s = ei[e], d = ei[EE + e];
        int pos = rowptr[d] + atomicAdd(&fill[d], 1);
        esorted[pos] = s;
    }
}

// ---------------- fused: weight prep (blocks 0..10) + zero cnt/fill (blocks 11..42) ----------------
__global__ __launch_bounds__(256) void prep_fused(const float* __restrict__ W1, const float* __restrict__ Wq,
                                                  const float* __restrict__ Wk, const float* __restrict__ Wv,
                                                  const float* __restrict__ W2, f16* __restrict__ Wt,
                                                  int4* __restrict__ zbuf) {
    int b = blockIdx.x;  // 0=W1, 1..3=Wq[l], 4..6=Wk[l], 7..9=Wv[l], 10=W2, 11..42 = zero 128KB
    int t = threadIdx.x;
    if (b >= 11) {
        zbuf[(b - 11) * 256 + t] = make_int4(0, 0, 0, 0);
        return;
    }
    f16* dst = Wt + (size_t)b * 16384;
    if (b == 10) {
        int oc = t & 63, k0 = (t >> 6) * 32;
        for (int kk = 0; kk < 32; ++kk) {
            int k = k0 + kk;
            dst[oc * 128 + k] = (f16)W2[(size_t)k * 64 + oc];
        }
        return;
    }
    const float* src = (b == 0) ? W1
                     : (b < 4)  ? Wq + (size_t)(b - 1) * 16384
                     : (b < 7)  ? Wk + (size_t)(b - 4) * 16384
                                : Wv + (size_t)(b - 7) * 16384;
    int oc = t >> 1;
    int k0 = (t & 1) * 64;
    for (int kk = 0; kk < 64; ++kk) {
        int k = k0 + kk;
        dst[oc * 128 + k] = (f16)src[k * 128 + oc];
    }
}

// ---------------- MFMA GEMM ----------------
// mode 0=f32 out, 1=f16+relu, 2=f16 raw, 3=fused final: relu -> @W2t -> +b2 -> log_softmax -> f32 out
struct GJob {
    const void* in; const f16* Wt; const float* bias; const float* rowscale;
    void* out; int ldi; int ldo; int mode; int inF32;
    const f16* Wt2; const float* bias2;
};
struct GJobs { GJob j[7]; };

__global__ __launch_bounds__(256) void gemm_mfma(GJobs jobs, int nrows) {
    const GJob jb = jobs.j[blockIdx.y];
    __shared__ f16 Xl[64 * 128];
    __shared__ f16 Wl[128 * 128];
    const int t = threadIdx.x;
    const int row0 = blockIdx.x * 64;

    half8 zero8;
#pragma unroll
    for (int z = 0; z < 8; ++z) zero8[z] = (f16)0.f;

#pragma unroll
    for (int it = 0; it < 4; ++it) {
        int idx = t + it * 256;
        int r = idx >> 4, c = idx & 15;
        int gr = row0 + r;
        half8 v = zero8;
        if (gr < nrows) {
            if (jb.inF32) {
                const float* fin = (const float*)jb.in + (size_t)gr * jb.ldi + c * 8;
                float4 f0 = ((const float4*)fin)[0];
                float4 f1 = ((const float4*)fin)[1];
                v[0] = (f16)f0.x; v[1] = (f16)f0.y; v[2] = (f16)f0.z; v[3] = (f16)f0.w;
                v[4] = (f16)f1.x; v[5] = (f16)f1.y; v[6] = (f16)f1.z; v[7] = (f16)f1.w;
            } else {
                v = *(const half8*)((const f16*)jb.in + (size_t)gr * jb.ldi + c * 8);
            }
        }
        *(half8*)((char*)Xl + r * 256 + ((c * 16) ^ ((r & 7) << 4))) = v;
    }
#pragma unroll
    for (int it = 0; it < 8; ++it) {
        int idx = t + it * 256;
        int r = idx >> 4, c = idx & 15;
        half8 v = *(const half8*)(jb.Wt + (size_t)r * 128 + c * 8);
        *(half8*)((char*)Wl + r * 256 + ((c * 16) ^ ((r & 7) << 4))) = v;
    }
    __syncthreads();

    const int w = t >> 6, l = t & 63;
    const int lr = l & 15;
    const int lk = l >> 4;

    f32x4 acc[8];
#pragma unroll
    for (int tn = 0; tn < 8; ++tn)
#pragma unroll
        for (int i = 0; i < 4; ++i) acc[tn][i] = 0.f;

    const int arow = w * 16 + lr;
    const int axor = (arow & 7) << 4;
    const int bxor = (lr & 7) << 4;

#pragma unroll
    for (int ks = 0; ks < 4; ++ks) {
        int koff = (ks * 4 + lk) * 16;
        half8 a = *(const half8*)((const char*)Xl + arow * 256 + (koff ^ axor));
#pragma unroll
        for (int tn = 0; tn < 8; ++tn) {
            int oc = tn * 16 + lr;
            half8 b = *(const half8*)((const char*)Wl + oc * 256 + (koff ^ bxor));
            acc[tn] = __builtin_amdgcn_mfma_f32_16x16x32_f16(a, b, acc[tn], 0, 0, 0);
        }
    }

    const int rbase = row0 + w * 16 + (lk << 2);
    float brs[4];
#pragma unroll
    for (int i = 0; i < 4; ++i)
        brs[i] = jb.rowscale ? ((rbase + i < nrows) ? jb.rowscale[rbase + i] : 0.f) : 1.0f;
    float bsv[8];
#pragma unroll
    for (int tn = 0; tn < 8; ++tn) bsv[tn] = jb.bias[tn * 16 + lr];

    if (jb.mode == 0) {
        float* op = (float*)jb.out;
#pragma unroll
        for (int tn = 0; tn < 8; ++tn)
#pragma unroll
            for (int i = 0; i < 4; ++i) {
                int gr = rbase + i;
                if (gr < nrows) op[(size_t)gr * jb.ldo + tn * 16 + lr] = acc[tn][i] + brs[i] * bsv[tn];
            }
    } else if (jb.mode == 1) {
        f16* op = (f16*)jb.out;
#pragma unroll
        for (int tn = 0; tn < 8; ++tn)
#pragma unroll
            for (int i = 0; i < 4; ++i) {
                int gr = rbase + i;
                if (gr < nrows) op[(size_t)gr * jb.ldo + tn * 16 + lr] = (f16)fmaxf(acc[tn][i] + brs[i] * bsv[tn], 0.f);
            }
    } else if (jb.mode == 2) {
        f16* op = (f16*)jb.out;
#pragma unroll
        for (int tn = 0; tn < 8; ++tn)
#pragma unroll
            for (int i = 0; i < 4; ++i) {
                int gr = rbase + i;
                if (gr < nrows) op[(size_t)gr * jb.ldo + tn * 16 + lr] = (f16)(acc[tn][i] + brs[i] * bsv[tn]);
            }
    } else {
        // mode 3: h3 = relu(acc + brs*bsv) -> Xl (swizzled); stage W2t -> Wl; MFMA vs W2t; +b2; log_softmax
        __syncthreads();  // everyone done reading Xl/Wl
#pragma unroll
        for (int tn = 0; tn < 8; ++tn)
#pragma unroll
            for (int i = 0; i < 4; ++i) {
                f16 v = (f16)fmaxf(acc[tn][i] + brs[i] * bsv[tn], 0.f);
                int lrow = w * 16 + (lk << 2) + i;
                int col = tn * 16 + lr;
                int byte = lrow * 256 + ((((col >> 3) * 16) ^ ((lrow & 7) << 4))) + (col & 7) * 2;
                *(f16*)((char*)Xl + byte) = v;
            }
#pragma unroll
        for (int it = 0; it < 4; ++it) {  // W2t: 64 rows x 16 chunks
            int idx = t + it * 256;
            int r = idx >> 4, c = idx & 15;
            half8 v = *(const half8*)(jb.Wt2 + (size_t)r * 128 + c * 8);
            *(half8*)((char*)Wl + r * 256 + ((c * 16) ^ ((r & 7) << 4))) = v;
        }
        __syncthreads();

        f32x4 acc2[4];
#pragma unroll
        for (int tn = 0; tn < 4; ++tn)
#pragma unroll
            for (int i = 0; i < 4; ++i) acc2[tn][i] = 0.f;
#pragma unroll
        for (int ks = 0; ks < 4; ++ks) {
            int koff = (ks * 4 + lk) * 16;
            half8 a = *(const half8*)((const char*)Xl + arow * 256 + (koff ^ axor));
#pragma unroll
            for (int tn = 0; tn < 4; ++tn) {
                int oc = tn * 16 + lr;
                half8 b = *(const half8*)((const char*)Wl + oc * 256 + (koff ^ bxor));
                acc2[tn] = __builtin_amdgcn_mfma_f32_16x16x32_f16(a, b, acc2[tn], 0, 0, 0);
            }
        }
        float bs2[4];
#pragma unroll
        for (int tn = 0; tn < 4; ++tn) bs2[tn] = jb.bias2[tn * 16 + lr];
#pragma unroll
        for (int i = 0; i < 4; ++i) {
            float lg[4];
#pragma unroll
            for (int tn = 0; tn < 4; ++tn) lg[tn] = acc2[tn][i] + bs2[tn];
            float m = fmaxf(fmaxf(lg[0], lg[1]), fmaxf(lg[2], lg[3]));
#pragma unroll
            for (int sft = 1; sft <= 8; sft <<= 1) m = fmaxf(m, __shfl_xor(m, sft));
            float den = 0.f;
#pragma unroll
            for (int tn = 0; tn < 4; ++tn) den += __expf(lg[tn] - m);
#pragma unroll
            for (int sft = 1; sft <= 8; sft <<= 1) den += __shfl_xor(den, sft);
            float lden = logf(den);
            int gr = rbase + i;
            if (gr < nrows) {
                float* op = (float*)jb.out + (size_t)gr * jb.ldo;
#pragma unroll
                for (int tn = 0; tn < 4; ++tn) op[tn * 16 + lr] = lg[tn] - m - lden;
            }
        }
    }
}

// ---------------- layer-1 GCN aggregation, quarter-wave (4 edges/wave) ----------------
__global__ __launch_bounds__(256) void sgather5(
    const int* __restrict__ rowptr, const int* __restrict__ esorted,
    const float* __restrict__ dinv,
    const f16* __restrict__ hsrc /* pack + HOFF */, f16* __restrict__ Sh, float* __restrict__ srow) {
    int d = (blockIdx.x * 256 + threadIdx.x) >> 6;
    int lam = threadIdx.x & 63;
    int qe = lam >> 4, le = lam & 15;
    if (d >= NN) return;
    int i0 = rowptr[d], nE = rowptr[d + 1] - i0 + 1;  // + self-loop (j == nE-1); j >= nE: w=0
    float dvd = dinv[d];
    float u[8];
#pragma unroll
    for (int i = 0; i < 8; ++i) u[i] = 0.f;
    float ssum = 0.f;

    auto ldb = [&](int b, float& w, half8& h) {
        int j = b + qe;
        int s = (j < nE - 1) ? esorted[i0 + j] : d;
        w = (j < nE) ? dinv[s] : 0.f;
        h = *(const half8*)(hsrc + (size_t)s * PSTR + le * 8);
    };
    auto cmp = [&](float w, const half8& h) {
#pragma unroll
        for (int i = 0; i < 8; ++i) u[i] = fmaf(w, (float)h[i], u[i]);
        ssum += w;
    };

    float wA, wB; half8 hA, hB;
    ldb(0, wA, hA);
    for (int b = 0; b < nE; b += 8) {
        ldb(b + 4, wB, hB);
        cmp(wA, hA);
        ldb(b + 8, wA, hA);
        cmp(wB, hB);
    }
    // reduce across the 4 edge-slots
#pragma unroll
    for (int i = 0; i < 8; ++i) {
        u[i] += __shfl_xor(u[i], 16);
        u[i] += __shfl_xor(u[i], 32);
    }
    ssum += __shfl_xor(ssum, 16);
    ssum += __shfl_xor(ssum, 32);
    if (qe == 0) {
        half8 o;
#pragma unroll
        for (int i = 0; i < 8; ++i) o[i] = (f16)(dvd * u[i]);
        *(half8*)(Sh + (size_t)d * 128 + le * 8) = o;
        if (le == 0) srow[d] = dvd * ssum;
    }
}

// ---------------- node attention (deferred V), quarter-wave: 4 edges/wave, 16B/lane ----------------
// lane: qe = lam>>4 (edge slot), le = lam&15 (channels [8*le,8*le+8), head = le>>1)
// KS0/KS1/KS2: k-slot index in pack for levels 0/1/2 (compile-time permutation)
template<int L, int KS0, int KS1, int KS2>
__global__ __launch_bounds__(256) void node_attn5(
    const int* __restrict__ rowptr, const int* __restrict__ esorted,
    const float* __restrict__ dinv,
    const f16* __restrict__ qh, const f16* __restrict__ pack,
    f16* __restrict__ uh) {
    constexpr int KSLOT[3] = {KS0, KS1, KS2};
    int d = (blockIdx.x * 256 + threadIdx.x) >> 6;
    int lam = threadIdx.x & 63;
    int qe = lam >> 4, le = lam & 15;
    if (d >= NN) return;
    int i0 = rowptr[d], nE = rowptr[d + 1] - i0 + 1;  // self-loop at j == nE-1; j >= nE: w=0
    float dvd = dinv[d];
    half8 q8 = *(const half8*)(qh + (size_t)d * 128 + le * 8);
    const f16x2* qp = (const f16x2*)&q8;
    float u[8];
#pragma unroll
    for (int i = 0; i < 8; ++i) u[i] = 0.f;

    auto ldb = [&](int b, float& w, half8 (&k)[L], half8 (&h)[L]) {
        int j = b + qe;
        int s = (j < nE - 1) ? esorted[i0 + j] : d;
        w = (j < nE) ? dinv[s] : 0.f;
        const f16* bp = pack + (size_t)s * PSTR + le * 8;
#pragma unroll
        for (int l = 0; l < L; ++l) {
            k[l] = *(const half8*)(bp + KSLOT[l] * 128);
            h[l] = *(const half8*)(bp + HOFF + l * 128);
        }
    };
    auto cmp = [&](float w, const half8 (&k)[L], const half8 (&h)[L]) {
        float sc[L];
#pragma unroll
        for (int l = 0; l < L; ++l) {
            const f16x2* kp = (const f16x2*)&k[l];
            float p = 0.f;
#pragma unroll
            for (int i = 0; i < 4; ++i) p = fdot2(qp[i], kp[i], p);
            p += __shfl_xor(p, 1);  // partner lane holds the head's other 8 channels
            sc[l] = p * 0.25f;      // 1/sqrt(16)
        }
        float m = sc[0];
#pragma unroll
        for (int l = 1; l < L; ++l) m = fmaxf(m, sc[l]);
        float den = 0.f;
#pragma unroll
        for (int l = 0; l < L; ++l) { sc[l] = __expf(sc[l] - m); den += sc[l]; }
        float wg = w * __builtin_amdgcn_rcpf(den);
#pragma unroll
        for (int l = 0; l < L; ++l) {
            float a = sc[l] * wg;
#pragma unroll
            for (int i = 0; i < 8; ++i) u[i] = fmaf(a, (float)h[l][i], u[i]);
        }
    };

    float wA, wB; half8 kA[L], hA[L], kB[L], hB[L];
    ldb(0, wA, kA, hA);
    for (int b = 0; b < nE; b += 8) {
        ldb(b + 4, wB, kB, hB);
        cmp(wA, kA, hA);
        ldb(b + 8, wA, kA, hA);
        cmp(wB, kB, hB);
    }
    // reduce across the 4 edge-slots
#pragma unroll
    for (int i = 0; i < 8; ++i) {
        u[i] += __shfl_xor(u[i], 16);
        u[i] += __shfl_xor(u[i], 32);
    }
    if (qe == 0) {
        half8 o;
#pragma unroll
        for (int i = 0; i < 8; ++i) o[i] = (f16)(dvd * u[i]);
        *(half8*)(uh + (size_t)d * 128 + le * 8) = o;
    }
}

extern "C" void kernel_launch(void* const* d_in, const int* in_sizes, int n_in,
                              void* d_out, int out_size, void* d_ws, size_t ws_size,
                              hipStream_t stream) {
    (void)in_sizes; (void)n_in; (void)out_size; (void)ws_size;
    const float* x  = (const float*)d_in[0];
    const int*   ei = (const int*)d_in[1];
    const float* W1 = (const float*)d_in[2];
    const float* b1 = (const float*)d_in[3];
    const float* Wq = (const float*)d_in[4];
    const float* bq = (const float*)d_in[5];
    const float* Wk = (const float*)d_in[6];
    const float* bk = (const float*)d_in[7];
    const float* Wv = (const float*)d_in[8];
    const float* bv = (const float*)d_in[9];
    const float* W2 = (const float*)d_in[10];
    const float* b2 = (const float*)d_in[11];
    float* out = (float*)d_out;

    // workspace layout (4-byte words)
    int*    cnt     = (int*)d_ws;                  // 16384
    int*    fill    = cnt + 16384;                 // 16384 (cnt+fill zeroed together)
    int*    rowptr  = fill + 16384;                // 16384 (NN+1)
    int*    esorted = rowptr + 16384;              // 163840
    float*  dinv    = (float*)(esorted + 163840);  // 16384
    float*  srow    = dinv + 16384;                // 16384
    f16*    pack    = (f16*)(srow + 16384);        // NN x 768 halves
    f16*    Sh      = pack + (size_t)NN * PSTR;    // N128
    f16*    qh      = Sh + N128;                   // N128
    f16*    uh      = qh + N128;                   // N128
    f16*    Wt      = uh + N128;                   // 11 x 16384

    prep_fused<<<43, 256, 0, stream>>>(W1, Wq, Wk, Wv, W2, Wt, (int4*)cnt);
    cnt_count<<<(EE + 255) / 256, 256, 0, stream>>>(ei + EE, cnt);
    scan_rowptr<<<1, 256, 0, stream>>>(cnt, rowptr, dinv);
    scatter_edges<<<(EE + 255) / 256, 256, 0, stream>>>(ei, rowptr, fill, esorted);

    const int gx = (NN + 63) / 64;  // 157
    auto WT = [&](int m) { return Wt + (size_t)m * 16384; };  // 0=W1,1..3=Wq,4..6=Wk,7..9=Wv,10=W2
    auto H  = [&](int lev) { return pack + HOFF + lev * 128; };  // h-level base (stride PSTR)
    auto K2 = [&](int slot) { return pack + slot * 128; };       // k-slot base (stride PSTR)

    {   // h0 = relu(x @ W1 + b1) -> pack  (reads f32 x directly)
        GJobs jobs{};
        jobs.j[0] = {x, WT(0), b1, nullptr, H(0), HID, PSTR, 1, 1, nullptr, nullptr};
        gemm_mfma<<<dim3(gx, 1), 256, 0, stream>>>(jobs, NN);
    }

    const int nblocks = (NN * 64 + 255) / 256;

    // ---- layer 1 (L=1: softmax over 1 level == identity -> GCN, deferred Wv1) ----
    sgather5<<<nblocks, 256, 0, stream>>>(rowptr, esorted, dinv, pack + HOFF, Sh, srow);
    {   // h1 = relu(S @ Wv1 + srow*bv1) -> pack
        GJobs jobs{};
        jobs.j[0] = {Sh, WT(7), bv, srow, H(1), HID, PSTR, 1, 0, nullptr, nullptr};
        gemm_mfma<<<dim3(gx, 1), 256, 0, stream>>>(jobs, NN);
    }

    {   // layer-2 qk dispatch + EARLY layer-3 k3_0 job (needs only h0):
        // q2 = h1@Wq[1] -> qh; k2_0 = h0@Wk[1] -> slot0; k2_1 = h1@Wk[1] -> slot1;
        // k3_0 = h0@Wk[2] -> spare slot2 (layer-2 attn only reads slots 0,1)
        GJobs jobs{};
        jobs.j[0] = {H(1), WT(2), bq + HID,     nullptr, qh,    PSTR, HID,  2, 0, nullptr, nullptr};
        jobs.j[1] = {H(0), WT(5), bk + HID,     nullptr, K2(0), PSTR, PSTR, 2, 0, nullptr, nullptr};
        jobs.j[2] = {H(1), WT(5), bk + HID,     nullptr, K2(1), PSTR, PSTR, 2, 0, nullptr, nullptr};
        jobs.j[3] = {H(0), WT(6), bk + 2 * HID, nullptr, K2(2), PSTR, PSTR, 2, 0, nullptr, nullptr};
        gemm_mfma<<<dim3(gx, 4), 256, 0, stream>>>(jobs, NN);
    }

    node_attn5<2, 0, 1, 2><<<nblocks, 256, 0, stream>>>(rowptr, esorted, dinv, qh, pack, uh);

    {   // h2 = relu(u @ Wv2 + srow*bv2) -> pack
        GJobs vjob{};
        vjob.j[0] = {uh, WT(8), bv + HID, srow, H(2), HID, PSTR, 1, 0, nullptr, nullptr};
        gemm_mfma<<<dim3(gx, 1), 256, 0, stream>>>(vjob, NN);
    }

    {   // layer-3 qk dispatch: q3 = h2@Wq[2] -> qh; k3_1 = h1@Wk[2] -> slot0; k3_2 = h2@Wk[2] -> slot1
        // (k3_0 already in slot2 from the early job; slots 0,1 are free after attn<2>)
        GJobs jobs{};
        jobs.j[0] = {H(2), WT(3), bq + 2 * HID, nullptr, qh,    PSTR, HID,  2, 0, nullptr, nullptr};
        jobs.j[1] = {H(1), WT(6), bk + 2 * HID, nullptr, K2(0), PSTR, PSTR, 2, 0, nullptr, nullptr};
        jobs.j[2] = {H(2), WT(6), bk + 2 * HID, nullptr, K2(1), PSTR, PSTR, 2, 0, nullptr, nullptr};
        gemm_mfma<<<dim3(gx, 3), 256, 0, stream>>>(jobs, NN);
    }

    // attn<3> with permuted k slots: lev0 -> slot2, lev1 -> slot0, lev2 -> slot1
    node_attn5<3, 2, 0, 1><<<nblocks, 256, 0, stream>>>(rowptr, esorted, dinv, qh, pack, uh);

    {   // fused: h3 = relu(u @ Wv3 + srow*bv3); out = log_softmax(h3 @ W2 + b2)
        GJobs vjob{};
        vjob.j[0] = {uh, WT(9), bv + 2 * HID, srow, out, HID, 64, 3, 0, WT(10), b2};
        gemm_mfma<<<dim3(gx, 1), 256, 0, stream>>>(vjob, NN);
    }
}